// Round 1
// baseline (268.608 us; speedup 1.0000x reference)
//
#include <hip/hip_runtime.h>

// GCLSTM with H=C=None collapses to: gates from x@Wx only (conv term = bconv
// constant), forget gate dead (C_prev=0), graph entirely unused.
//   h1 = sig(zo)*tanh(sig(zi)*tanh(zc)),  z* = x@Wx1[:,gate]+bx1+bconv1
//   h2 = same with Wx2/bx2/bconv2
//   out = relu(h2)@Wl + bl
// Strategy: pack kernel transposes the 3 live gate columns of Wx1/Wx2 into
// d_ws ([3][50][128] and [3][20][50], k contiguous) + fused biases. Main
// kernel: 1 thread = 1 node; x row in 128 VGPRs; weights read uniformly
// (scalar loads); float2 accumulation for v_pk_fma_f32.

#define NODES 100000

typedef float v2f __attribute__((ext_vector_type(2)));

__device__ __forceinline__ float fast_sigmoid(float z) {
  float t = __builtin_amdgcn_exp2f(z * -1.44269504088896f);
  return __builtin_amdgcn_rcpf(1.0f + t);
}
__device__ __forceinline__ float fast_tanh(float z) {
  // tanh(z) = 1 - 2/(e^{2z}+1); exp->inf / ->0 give correct +-1 saturation
  float t = __builtin_amdgcn_exp2f(z * 2.88539008177793f);
  return 1.0f - 2.0f * __builtin_amdgcn_rcpf(t + 1.0f);
}

// ws float layout:
//   [0      : 19200) WT1 [3][50][128]  (gates i,c,o; k contiguous)
//   [19200  : 19350) B1  [3][50]       bx1+bconv1 fused
//   [19350  : 22350) WT2 [3][20][50]
//   [22350  : 22410) B2  [3][20]
__global__ void pack_weights(const float* __restrict__ Wx1,
                             const float* __restrict__ bx1,
                             const float* __restrict__ bconv1,
                             const float* __restrict__ Wx2,
                             const float* __restrict__ bx2,
                             const float* __restrict__ bconv2,
                             float* __restrict__ ws) {
  const int gmap[3] = {0, 2, 3};  // live gates: i, c, o
  const int stride = gridDim.x * blockDim.x;
  const int tid = blockIdx.x * blockDim.x + threadIdx.x;

  for (int idx = tid; idx < 3 * 50 * 128; idx += stride) {
    int k = idx & 127;
    int j = (idx >> 7) % 50;
    int g = idx / (50 * 128);
    ws[idx] = Wx1[k * 200 + gmap[g] * 50 + j];
  }
  for (int idx = tid; idx < 150; idx += stride) {
    int j = idx % 50;
    int g = idx / 50;
    ws[19200 + idx] = bx1[gmap[g] * 50 + j] + bconv1[gmap[g] * 50 + j];
  }
  for (int idx = tid; idx < 3 * 20 * 50; idx += stride) {
    int k = idx % 50;
    int j = (idx / 50) % 20;
    int g = idx / (20 * 50);
    ws[19350 + idx] = Wx2[k * 80 + gmap[g] * 20 + j];
  }
  for (int idx = tid; idx < 60; idx += stride) {
    int j = idx % 20;
    int g = idx / 20;
    ws[22350 + idx] = bx2[gmap[g] * 20 + j] + bconv2[gmap[g] * 20 + j];
  }
}

__global__ __launch_bounds__(64) void gclstm_main(
    const float* __restrict__ x, const float* __restrict__ wsf,
    const float* __restrict__ Wl, const float* __restrict__ blp,
    float* __restrict__ out) {
  const float* WT1 = wsf;
  const float* B1  = wsf + 19200;
  const float* WT2 = wsf + 19350;
  const float* B2  = wsf + 22350;

  // 51-float row pad: lane stride 51 -> gcd(51,32)=1 -> conflict-free-ish (2-way)
  __shared__ float h1s[64 * 51];

  const int tid = threadIdx.x;
  const int n = blockIdx.x * 64 + tid;
  const bool valid = (n < NODES);
  const int nn = valid ? n : (NODES - 1);

  // x row -> 64 float2 regs
  v2f xv[64];
  {
    const float4* xr = (const float4*)(x + (size_t)nn * 128);
#pragma unroll
    for (int i = 0; i < 32; ++i) {
      float4 t = xr[i];
      v2f a; a.x = t.x; a.y = t.y;
      v2f b; b.x = t.z; b.y = t.w;
      xv[2 * i] = a;
      xv[2 * i + 1] = b;
    }
  }

  // ---- layer 1: 50 channels x 3 gates, K=128 ----
#pragma unroll 1
  for (int j = 0; j < 50; ++j) {
    const v2f* wi = (const v2f*)(WT1 + (size_t)j * 128);
    const v2f* wc = (const v2f*)(WT1 + (size_t)(50 + j) * 128);
    const v2f* wo = (const v2f*)(WT1 + (size_t)(100 + j) * 128);
    v2f ai = {B1[j], 0.f};
    v2f ac = {B1[50 + j], 0.f};
    v2f ao = {B1[100 + j], 0.f};
#pragma unroll
    for (int k = 0; k < 64; ++k) {
      ai += xv[k] * wi[k];
      ac += xv[k] * wc[k];
      ao += xv[k] * wo[k];
    }
    float I = fast_sigmoid(ai.x + ai.y);
    float T = fast_tanh(ac.x + ac.y);
    float O = fast_sigmoid(ao.x + ao.y);
    h1s[tid * 51 + j] = O * fast_tanh(I * T);
  }

  // h1 back to regs (own lane's data only; no barrier needed)
  v2f hv[25];
#pragma unroll
  for (int k = 0; k < 25; ++k) {
    v2f a;
    a.x = h1s[tid * 51 + 2 * k];
    a.y = h1s[tid * 51 + 2 * k + 1];
    hv[k] = a;
  }

  // ---- layer 2 (K=50) fused with relu + head ----
  float o = 0.f;
#pragma unroll 1
  for (int j = 0; j < 20; ++j) {
    const v2f* wi = (const v2f*)(WT2 + (size_t)j * 50);
    const v2f* wc = (const v2f*)(WT2 + (size_t)(20 + j) * 50);
    const v2f* wo = (const v2f*)(WT2 + (size_t)(40 + j) * 50);
    v2f ai = {B2[j], 0.f};
    v2f ac = {B2[20 + j], 0.f};
    v2f ao = {B2[40 + j], 0.f};
#pragma unroll
    for (int k = 0; k < 25; ++k) {
      ai += hv[k] * wi[k];
      ac += hv[k] * wc[k];
      ao += hv[k] * wo[k];
    }
    float I = fast_sigmoid(ai.x + ai.y);
    float T = fast_tanh(ac.x + ac.y);
    float O = fast_sigmoid(ao.x + ao.y);
    float h2 = O * fast_tanh(I * T);
    o = fmaf(fmaxf(h2, 0.f), Wl[j], o);
  }

  if (valid) out[n] = o + blp[0];
}

extern "C" void kernel_launch(void* const* d_in, const int* in_sizes, int n_in,
                              void* d_out, int out_size, void* d_ws, size_t ws_size,
                              hipStream_t stream) {
  (void)in_sizes; (void)n_in; (void)out_size; (void)ws_size;
  const float* x      = (const float*)d_in[0];
  // d_in[1] edge_index, d_in[2] edge_weight, d_in[5] theta1, d_in[9] theta2: dead
  const float* Wx1    = (const float*)d_in[3];
  const float* bx1    = (const float*)d_in[4];
  const float* bconv1 = (const float*)d_in[6];
  const float* Wx2    = (const float*)d_in[7];
  const float* bx2    = (const float*)d_in[8];
  const float* bconv2 = (const float*)d_in[10];
  const float* Wl     = (const float*)d_in[11];
  const float* bl     = (const float*)d_in[12];
  float* ws = (float*)d_ws;  // needs 22410 floats (~90 KB)

  hipLaunchKernelGGL(pack_weights, dim3(64), dim3(256), 0, stream,
                     Wx1, bx1, bconv1, Wx2, bx2, bconv2, ws);
  hipLaunchKernelGGL(gclstm_main, dim3((NODES + 63) / 64), dim3(64), 0, stream,
                     x, ws, Wl, bl, (float*)d_out);
}